// Round 8
// baseline (282.867 us; speedup 1.0000x reference)
//
#include <hip/hip_runtime.h>
#include <math.h>

// Problem constants (fixed by reference)
#define B_TOT   256
#define N_TOT   2304
#define IN_DIM  8
#define NC      10      // NUM_CLASSES
#define OD      16      // OUT_DIM
#define CD      160     // NC*OD
#define RBIAS   0.1f

// Tiling: wave-per-class layout. Block = 10 waves (c=0..9) × 64 lanes (b).
#define BTILE    64                      // b per block (= wave lanes)
#define NS       192                     // n-slices (grid.y); grid = 4*192 = 768 = 3 blk/CU (30/32 waves)
#define NPB      (N_TOT / NS)            // 12 n per block
#define NTHREADS 640                     // 10 waves
#define XR       (NPB * IN_DIM + 4)      // 100: x row stride
#define LB       72                      // logit board row stride
#define NF4      (B_TOT * CD / 4)        // 10240 float4 per partial slab
#define YGRP     8                       // reduce stage-A groups
#define YPER     (NS / YGRP)             // 24 slabs per group

// One routing round. Wave c, lane b. Thread owns u[16] for (b0+b, class c).
// W[n,i,c*16..+16) is wave-uniform -> scalar loads; W never touches LDS/VGPRs.
// MODE 0: round 0 — cw uniform, no logits/barriers; 0.1 scale folded downstream.
// MODE 1: round 1 — S = 0.1*sum(part2_0) + 0.1
// MODE 2: round 2 — S = 0.1*sum(part2_0) + sum(part2_1) + 0.2
template <int MODE>
__global__ __launch_bounds__(NTHREADS) void routing_round(
    const float* __restrict__ x,       // [B, N, 8]
    const float* __restrict__ W,       // [N, 8, 160]
    const float* __restrict__ p2a,     // [YGRP, B, 160] round-0 group sums
    const float* __restrict__ p2b,     // [YGRP, B, 160] round-1 group sums
    float* __restrict__ part)          // [NS, B, 160]
{
    __shared__ float sh_x[BTILE * XR];            // 25.6 KB
    __shared__ float sh_lg[2][NC * LB];           // 5.8 KB

    const int tid = threadIdx.x;
    const int b0  = blockIdx.x * BTILE;
    const int n0  = blockIdx.y * NPB;
    const int b   = tid & 63;
    // Force wave-uniformity so W indexing becomes scalar (s_load).
    const int cu  = __builtin_amdgcn_readfirstlane(tid >> 6);

    // ---- stage x tile: [64 b][96 floats], coalesced float4
    {
        const int XT4 = BTILE * (NPB * IN_DIM / 4);   // 64*24 = 1536
        for (int k = tid; k < XT4; k += NTHREADS) {
            int bb   = k / (NPB * 2);
            int off4 = k - bb * (NPB * 2);
            float4 v = *(const float4*)(x + ((size_t)(b0 + bb) * N_TOT + n0) * IN_DIM + off4 * 4);
            *(float4*)(&sh_x[bb * XR + off4 * 4]) = v;
        }
    }

    // ---- S fragment for (b, c): rebuilt inline from group slabs (no S_acc kernel)
    float S[OD];
    if (MODE != 0) {
        const size_t off = (size_t)(b0 + b) * CD + cu * OD;
        #pragma unroll
        for (int d = 0; d < OD; d++) S[d] = 0.f;
        #pragma unroll
        for (int k = 0; k < YGRP; k++) {
            const float4* pa = (const float4*)(p2a + (size_t)k * (B_TOT * CD) + off);
            #pragma unroll
            for (int q = 0; q < 4; q++) {
                float4 t = pa[q];
                S[q*4+0] += t.x; S[q*4+1] += t.y; S[q*4+2] += t.z; S[q*4+3] += t.w;
            }
        }
        #pragma unroll
        for (int d = 0; d < OD; d++) S[d] = S[d] * 0.1f + RBIAS;   // s0 + bias
        if (MODE == 2) {
            #pragma unroll
            for (int k = 0; k < YGRP; k++) {
                const float4* pb = (const float4*)(p2b + (size_t)k * (B_TOT * CD) + off);
                #pragma unroll
                for (int q = 0; q < 4; q++) {
                    float4 t = pb[q];
                    S[q*4+0] += t.x; S[q*4+1] += t.y; S[q*4+2] += t.z; S[q*4+3] += t.w;
                }
            }
            #pragma unroll
            for (int d = 0; d < OD; d++) S[d] += RBIAS;            // + s1 + bias
        }
    }

    float acc[OD];
    #pragma unroll
    for (int d = 0; d < OD; d++) acc[d] = 0.f;

    __syncthreads();   // sh_x ready

    const float* Wc = W + cu * OD;    // wave-uniform base

    for (int nn = 0; nn < NPB; nn++) {
        // x[b, n0+nn, 0..7] from LDS (2× ds_read_b128, the only per-iter LDS reads)
        float xf[IN_DIM];
        {
            const float4* xp = (const float4*)(&sh_x[b * XR + nn * IN_DIM]);
            ((float4*)xf)[0] = xp[0];
            ((float4*)xf)[1] = xp[1];
        }

        // u[16] = sum_i x_i * W[n,i,c*16+d]  — W operand is SGPR (scalar loads)
        const float* Wn = Wc + (size_t)(n0 + nn) * (IN_DIM * CD);
        float u[OD];
        #pragma unroll
        for (int d = 0; d < OD; d++) u[d] = xf[0] * Wn[d];
        #pragma unroll
        for (int i = 1; i < IN_DIM; i++) {
            const float* Wi = Wn + i * CD;
            #pragma unroll
            for (int d = 0; d < OD; d++) u[d] = fmaf(xf[i], Wi[d], u[d]);
        }

        if (MODE != 0) {
            const int cur = nn & 1;
            // logit fully in-thread
            float lg = 0.f;
            #pragma unroll
            for (int d = 0; d < OD; d++) lg = fmaf(u[d], S[d], lg);
            sh_lg[cur][cu * LB + b] = lg;
            __syncthreads();   // board ready

            // softmax over the 10 classes for row b
            float m = -1e30f;
            float row[NC];
            #pragma unroll
            for (int k = 0; k < NC; k++) {
                row[k] = sh_lg[cur][k * LB + b];
                m = fmaxf(m, row[k]);
            }
            float den = 0.f;
            #pragma unroll
            for (int k = 0; k < NC; k++) den += __expf(row[k] - m);
            float cw = __expf(lg - m) / den;

            #pragma unroll
            for (int d = 0; d < OD; d++) acc[d] = fmaf(cw, u[d], acc[d]);
        } else {
            #pragma unroll
            for (int d = 0; d < OD; d++) acc[d] += u[d];   // 0.1 folded downstream
        }
    }

    // flush: plain stores to this block's private slab — NO atomics
    float* dst = part + ((size_t)blockIdx.y * B_TOT + (b0 + b)) * CD + cu * OD;
    #pragma unroll
    for (int q = 0; q < 4; q++)
        ((float4*)dst)[q] = ((float4*)acc)[q];
}

// Stage A: block (g-chunk, k) sums slabs y in [k*YPER, (k+1)*YPER) -> part2[k]
__global__ __launch_bounds__(256) void reduceA(
    const float* __restrict__ part,   // [NS, B, 160]
    float* __restrict__ part2)        // [YGRP, B, 160]
{
    int g = blockIdx.x * 256 + threadIdx.x;   // 0..NF4-1
    int k = blockIdx.y;
    const float4* p4 = (const float4*)part + (size_t)k * YPER * NF4 + g;
    float sx = 0.f, sy = 0.f, sz = 0.f, sw = 0.f;
    #pragma unroll 4
    for (int y = 0; y < YPER; y++) {
        float4 t = p4[(size_t)y * NF4];
        sx += t.x; sy += t.y; sz += t.z; sw += t.w;
    }
    float4 o = { sx, sy, sz, sw };
    ((float4*)part2)[(size_t)k * NF4 + g] = o;
}

// Final: sums round-2 group-slabs (+bias), squashes, writes v.
__global__ __launch_bounds__(256) void finalB(
    const float* __restrict__ part2,  // [YGRP, B, 160]
    float* __restrict__ v_out)
{
    int g = blockIdx.x * 256 + threadIdx.x;   // 0..NF4-1
    const float4* p4 = (const float4*)part2;
    float sx = 0.f, sy = 0.f, sz = 0.f, sw = 0.f;
    #pragma unroll
    for (int k = 0; k < YGRP; k++) {
        float4 t = p4[(size_t)k * NF4 + g];
        sx += t.x; sy += t.y; sz += t.z; sw += t.w;
    }
    sx += RBIAS; sy += RBIAS; sz += RBIAS; sw += RBIAS;
    // squash over 16 d = 4 consecutive lanes (one (b,c) row)
    float ss = sx * sx + sy * sy + sz * sz + sw * sw;
    ss += __shfl_xor(ss, 1, 64);
    ss += __shfl_xor(ss, 2, 64);
    float norm = sqrtf(ss);
    float k2 = norm / (1.0f + ss);
    float4 v = { sx * k2, sy * k2, sz * k2, sw * k2 };
    ((float4*)v_out)[g] = v;
}

extern "C" void kernel_launch(void* const* d_in, const int* in_sizes, int n_in,
                              void* d_out, int out_size, void* d_ws, size_t ws_size,
                              hipStream_t stream) {
    const float* x = (const float*)d_in[0];   // [256,2304,8]
    const float* W = (const float*)d_in[1];   // [2304,8,160]
    float* out = (float*)d_out;               // [256,10,16]

    // Workspace layout (all fully overwritten before read each call — re-poison safe)
    float* part  = (float*)d_ws;                            // NS * 40960  (~31.5 MB)
    float* p2_0  = part + (size_t)NS * B_TOT * CD;          // YGRP * 40960 (1.31 MB)
    float* p2_1  = p2_0 + (size_t)YGRP * B_TOT * CD;
    float* p2_2  = p2_1 + (size_t)YGRP * B_TOT * CD;

    // Round 0: uniform weights (0.1 folded into S-reconstruction downstream)
    routing_round<0><<<dim3(B_TOT / BTILE, NS), NTHREADS, 0, stream>>>(x, W, nullptr, nullptr, part);
    reduceA<<<dim3(NF4 / 256, YGRP), 256, 0, stream>>>(part, p2_0);

    // Round 1: S = 0.1*sum(p2_0) + 0.1
    routing_round<1><<<dim3(B_TOT / BTILE, NS), NTHREADS, 0, stream>>>(x, W, p2_0, nullptr, part);
    reduceA<<<dim3(NF4 / 256, YGRP), 256, 0, stream>>>(part, p2_1);

    // Round 2: S = 0.1*sum(p2_0) + sum(p2_1) + 0.2
    routing_round<2><<<dim3(B_TOT / BTILE, NS), NTHREADS, 0, stream>>>(x, W, p2_0, p2_1, part);
    reduceA<<<dim3(NF4 / 256, YGRP), 256, 0, stream>>>(part, p2_2);

    // Final: v = squash(sum(p2_2) + 0.1)
    finalB<<<NF4 / 256, 256, 0, stream>>>(p2_2, out);
}